// Round 11
// baseline (449.443 us; speedup 1.0000x reference)
//
#include <hip/hip_runtime.h>

constexpr int D  = 256;
constexpr int K  = 8192;
constexpr int N  = 32768;   // B*S
constexpr float TMARG = 0.5f;   // certified margin (err bound ~0.25 per score, 2x slack)
constexpr int  CAP  = 16384;    // flagged-row capacity (expected ~2700)
constexpr int  RCH  = 32;       // rescue K-chunks (256 codes each)

typedef _Float16 f16;
typedef f16   f16x8  __attribute__((ext_vector_type(8)));
typedef float f32x16 __attribute__((ext_vector_type(16)));

__device__ __forceinline__ void gload_lds16(const void* g, void* l) {
    __builtin_amdgcn_global_load_lds(
        (const __attribute__((address_space(1))) unsigned int*)g,
        (__attribute__((address_space(3))) unsigned int*)l,
        16, 0, 0);
}

// ============================================================================
// cbt layout (transposed 16B chunks): chunk s in [0,64), code k:
//   s in [0,32):  eh = fp16(e), d in [8s, 8s+8)
//   s in [32,64): el' = fp16((e-eh)*1024), d in [8(s-32), 8(s-32)+8)
//   stored at cbt[(s*8192 + k)*8 .. +8)
// Pipeline: esq+cvt -> vq16a (fp16 approx, top-2 margin) -> flagmerge
// (certified rows written; ambiguous rows compacted) -> rescue (exact 3-split
// over flagged rows x 32 K-chunks) -> fixup (merge partials, write).
// ============================================================================

__global__ void esq_kernel(const float* __restrict__ cb, float* __restrict__ esq,
                           int* __restrict__ cnt) {
    if (blockIdx.x == 0 && threadIdx.x == 0) *cnt = 0;
    const int lane = threadIdx.x & 63;
    const int code = (int)((blockIdx.x * (size_t)blockDim.x + threadIdx.x) >> 6);
    const float4 v = *reinterpret_cast<const float4*>(cb + (size_t)code * D + lane * 4);
    float s = v.x * v.x + v.y * v.y + v.z * v.z + v.w * v.w;
    #pragma unroll
    for (int m = 32; m >= 1; m >>= 1) s += __shfl_xor(s, m);
    if (lane == 0) esq[code] = s;
}

__global__ void cvt_t(const float* __restrict__ cb, f16* __restrict__ cbt) {
    const int g    = blockIdx.x * 256 + threadIdx.x;   // [0, 64*8192)
    const int s    = g >> 13;                          // chunk slot 0..63
    const int code = g & 8191;
    const float* src = cb + (size_t)code * D + (s & 31) * 8;
    const float4 a  = *reinterpret_cast<const float4*>(src);
    const float4 b2 = *reinterpret_cast<const float4*>(src + 4);
    const float vf[8] = {a.x, a.y, a.z, a.w, b2.x, b2.y, b2.z, b2.w};
    f16x8 o;
    if (s < 32) {
        #pragma unroll
        for (int e = 0; e < 8; ++e) o[e] = (f16)vf[e];
    } else {
        #pragma unroll
        for (int e = 0; e < 8; ++e) {
            f16 h = (f16)vf[e];
            o[e] = (f16)((vf[e] - (float)h) * 1024.0f);
        }
    }
    *reinterpret_cast<f16x8*>(cbt + ((size_t)s * 8192 + code) * 8) = o;
}

// -------- approx pass: fp16 zh*eh, 1 read + 1 MFMA per u, top-2 per row -----
// grid 768 = 256 row-groups x 3 K-chunks (85/85/86 k-tiles of 32 codes).
__launch_bounds__(256, 3)
__global__ void vq16a(const float* __restrict__ z, const f16* __restrict__ cbt,
                      const float* __restrict__ esq,
                      float* __restrict__ wv1, int* __restrict__ wi1,
                      float* __restrict__ wv2) {
    __shared__ f16 buf[2][8192];   // [32 slots][32 codes][8 f16] = 16 KB each

    const int tid  = threadIdx.x;
    const int w    = tid >> 6;
    const int l    = tid & 63;
    const int cid  = l & 31;
    const int half = l >> 5;
    const int kc   = blockIdx.x % 3;
    const int rg   = blockIdx.x / 3;
    const int kc0  = kc * 2720;
    const int NT   = (kc == 2) ? 86 : 85;
    const size_t wrow0 = (size_t)rg * 128 + w * 32;

    // A: zh = fp16(z) for 32 rows; lane l holds A[row=l&31][k = u*16+(l>>5)*8+e]
    f16x8 zh[16];
    {
        const float* zr = z + (wrow0 + cid) * D + half * 8;
        #pragma unroll
        for (int u = 0; u < 16; ++u) {
            float4 a  = *reinterpret_cast<const float4*>(zr + u * 16);
            float4 b2 = *reinterpret_cast<const float4*>(zr + u * 16 + 4);
            float vf[8] = {a.x, a.y, a.z, a.w, b2.x, b2.y, b2.z, b2.w};
            f16x8 h;
            #pragma unroll
            for (int e = 0; e < 8; ++e) h[e] = (f16)vf[e];
            zh[u] = h;
        }
    }

    float minv[16], mnv2[16];
    int   mini[16];
    #pragma unroll
    for (int g = 0; g < 16; ++g) { minv[g] = 3.0e38f; mnv2[g] = 3.0e38f; mini[g] = 0; }

    f32x16 acc = (f32x16)0.0f;

    // staging: wave w owns slots [8w, 8w+8); 4 instrs x 2 slots
    #pragma unroll
    for (int j = 0; j < 4; ++j) {
        const int s = w * 8 + 2 * j + half;
        gload_lds16(cbt + ((size_t)s * 8192 + kc0 + cid) * 8,
                    &buf[0][(w * 8 + 2 * j) * 256]);
    }
    __syncthreads();

    for (int kt = 0; kt < NT; ++kt) {
        const int  b        = kt & 1;
        const bool haveNext = (kt < NT - 1);

        if (haveNext) {
            const int k0n = kc0 + (kt + 1) * 32;
            #pragma unroll
            for (int j = 0; j < 4; ++j) {
                const int s = w * 8 + 2 * j + half;
                gload_lds16(cbt + ((size_t)s * 8192 + k0n + cid) * 8,
                            &buf[b ^ 1][(w * 8 + 2 * j) * 256]);
            }
        }
        const float es = esq[kc0 + kt * 32 + cid];

        const f16* Bp = &buf[b][0];
        __builtin_amdgcn_s_setprio(1);
        #pragma unroll
        for (int u = 0; u < 16; ++u) {
            f16x8 beh = *reinterpret_cast<const f16x8*>(Bp + ((2 * u + half) * 32 + cid) * 8);
            acc = __builtin_amdgcn_mfma_f32_32x32x16_f16(zh[u], beh, acc, 0, 0, 0);
        }
        __builtin_amdgcn_s_setprio(0);

        // top-2 epilogue (value2 has no index; ties -> margin 0 -> rescue)
        const int c0 = kc0 + kt * 32 + cid;
        #pragma unroll
        for (int g = 0; g < 16; ++g) {
            float s = fmaf(-2.0f, acc[g], es);
            if (s < minv[g])      { mnv2[g] = minv[g]; minv[g] = s; mini[g] = c0; }
            else if (s < mnv2[g]) { mnv2[g] = s; }
        }
        acc = (f32x16)0.0f;

        if (haveNext) __syncthreads();
    }

    // merge (v1,i1,v2) across the 32 lanes of each half
    #pragma unroll
    for (int g = 0; g < 16; ++g) {
        float v1 = minv[g], v2 = mnv2[g];
        int   i1 = mini[g];
        #pragma unroll
        for (int m = 1; m < 32; m <<= 1) {
            float ov1 = __shfl_xor(v1, m);
            int   oi1 = __shfl_xor(i1, m);
            float ov2 = __shfl_xor(v2, m);
            if (ov1 < v1 || (ov1 == v1 && oi1 < i1)) {
                v2 = fminf(v1, ov2); v1 = ov1; i1 = oi1;
            } else {
                v2 = fminf(v2, ov1);
            }
        }
        const size_t row = wrow0 + (g & 3) + 8 * (g >> 2) + 4 * half;
        if (cid == 0) {
            wv1[(size_t)kc * N + row] = v1;
            wi1[(size_t)kc * N + row] = i1;
            wv2[(size_t)kc * N + row] = v2;
        }
    }
}

// -------- merge 3 chunks; certified rows -> write; ambiguous -> compact -----
__global__ void flagmerge(const float* __restrict__ wv1, const int* __restrict__ wi1,
                          const float* __restrict__ wv2, const float* __restrict__ cb,
                          float* __restrict__ out, int* __restrict__ list,
                          int* __restrict__ cnt) {
    const int t    = threadIdx.x;
    const int r    = blockIdx.x * 16 + (t >> 4);
    const int l16  = t & 15;
    const int lane = t & 63;

    float v1 = wv1[r], v2 = wv2[r];
    int   i1 = wi1[r];
    #pragma unroll
    for (int c = 1; c < 3; ++c) {
        const float cv1 = wv1[(size_t)c * N + r];
        const int   ci1 = wi1[(size_t)c * N + r];
        const float cv2 = wv2[(size_t)c * N + r];
        if (cv1 < v1) { v2 = fminf(v1, cv2); v1 = cv1; i1 = ci1; }
        else          { v2 = fminf(v2, cv1); }
    }
    const bool flagged = (v2 - v1) < TMARG;

    int pos = -1;
    if (flagged && l16 == 0) pos = atomicAdd(cnt, 1);
    pos = __shfl(pos, (lane >> 4) << 4);   // broadcast within the 16-lane group

    if (flagged && pos < CAP) {
        if (l16 == 0) list[pos] = r;
        return;   // rescue + fixup will write this row
    }
    // certified (or overflow fallback): write idx + embedding
    if (l16 == 0) out[(size_t)N * D + r] = (float)i1;
    const float4* src = reinterpret_cast<const float4*>(cb + (size_t)i1 * D);
    float4*       dst = reinterpret_cast<float4*>(out + (size_t)r * D);
    #pragma unroll
    for (int it = 0; it < 4; ++it) dst[l16 + 16 * it] = src[l16 + 16 * it];
}

// -------- exact 3-split rescue over flagged rows x 32 K-chunks --------------
__launch_bounds__(256, 2)
__global__ void rescue(const float* __restrict__ z, const f16* __restrict__ cbt,
                       const float* __restrict__ esq, const int* __restrict__ list,
                       const int* __restrict__ cnt,
                       float* __restrict__ pv, int* __restrict__ pi) {
    const int rgi = blockIdx.x >> 5;
    const int kc  = blockIdx.x & (RCH - 1);
    const int cc  = min(*cnt, CAP);
    if (rgi * 128 >= cc) return;

    __shared__ f16 buf[2][16384];   // [64 slots][32 codes][8 f16] = 32 KB each

    const int tid  = threadIdx.x;
    const int w    = tid >> 6;
    const int l    = tid & 63;
    const int cid  = l & 31;
    const int half = l >> 5;
    const int kb   = kc * 256;      // 8 k-tiles of 32 codes

    const int myslot = rgi * 128 + w * 32 + cid;
    const int lrow   = list[min(myslot, cc - 1)];

    f16x8 zh[16], zl[16];
    {
        const float* zr = z + (size_t)lrow * D + half * 8;
        #pragma unroll
        for (int u = 0; u < 16; ++u) {
            float4 a  = *reinterpret_cast<const float4*>(zr + u * 16);
            float4 b2 = *reinterpret_cast<const float4*>(zr + u * 16 + 4);
            float vf[8] = {a.x, a.y, a.z, a.w, b2.x, b2.y, b2.z, b2.w};
            f16x8 h, lo;
            #pragma unroll
            for (int e = 0; e < 8; ++e) {
                f16 hh = (f16)vf[e];
                h[e]  = hh;
                lo[e] = (f16)((vf[e] - (float)hh) * 1024.0f);
            }
            zh[u] = h; zl[u] = lo;
        }
    }

    float minv[16];
    int   mini[16];
    #pragma unroll
    for (int g = 0; g < 16; ++g) { minv[g] = 3.0e38f; mini[g] = 0; }

    f32x16 accA = (f32x16)0.0f, accB = (f32x16)0.0f;

    #pragma unroll
    for (int j = 0; j < 8; ++j) {
        const int s = w * 16 + 2 * j + half;
        gload_lds16(cbt + ((size_t)s * 8192 + kb + cid) * 8,
                    &buf[0][(w * 16 + 2 * j) * 256]);
    }
    __syncthreads();

    for (int kt = 0; kt < 8; ++kt) {
        const int  b        = kt & 1;
        const bool haveNext = (kt < 7);

        if (haveNext) {
            const int k0n = kb + (kt + 1) * 32;
            #pragma unroll
            for (int j = 0; j < 8; ++j) {
                const int s = w * 16 + 2 * j + half;
                gload_lds16(cbt + ((size_t)s * 8192 + k0n + cid) * 8,
                            &buf[b ^ 1][(w * 16 + 2 * j) * 256]);
            }
        }
        const float es = esq[kb + kt * 32 + cid];

        const f16* Bp = &buf[b][0];
        #pragma unroll
        for (int u = 0; u < 16; ++u) {
            f16x8 beh = *reinterpret_cast<const f16x8*>(Bp + ((2 * u + half) * 32 + cid) * 8);
            f16x8 bel = *reinterpret_cast<const f16x8*>(Bp + ((32 + 2 * u + half) * 32 + cid) * 8);
            accA = __builtin_amdgcn_mfma_f32_32x32x16_f16(zh[u], beh, accA, 0, 0, 0);
            accB = __builtin_amdgcn_mfma_f32_32x32x16_f16(zl[u], beh, accB, 0, 0, 0);
            accB = __builtin_amdgcn_mfma_f32_32x32x16_f16(zh[u], bel, accB, 0, 0, 0);
        }

        const int c0 = kb + kt * 32 + cid;
        #pragma unroll
        for (int g = 0; g < 16; ++g) {
            float d = fmaf(accB[g], 0.0009765625f, accA[g]);
            float s = fmaf(-2.0f, d, es);
            if (s < minv[g]) { minv[g] = s; mini[g] = c0; }
        }
        accA = (f32x16)0.0f; accB = (f32x16)0.0f;

        if (haveNext) __syncthreads();
    }

    #pragma unroll
    for (int g = 0; g < 16; ++g) {
        float v   = minv[g];
        int   idx = mini[g];
        #pragma unroll
        for (int m = 1; m < 32; m <<= 1) {
            float ov = __shfl_xor(v, m);
            int   oi = __shfl_xor(idx, m);
            if (ov < v || (ov == v && oi < idx)) { v = ov; idx = oi; }
        }
        const int pos = rgi * 128 + w * 32 + (g & 3) + 8 * (g >> 2) + 4 * half;
        if (cid == 0 && pos < cc) {
            pv[(size_t)pos * RCH + kc] = v;
            pi[(size_t)pos * RCH + kc] = idx;
        }
    }
}

// -------- fixup: merge 32 chunk partials per flagged row, write output ------
__global__ void fixup(const int* __restrict__ list, const int* __restrict__ cnt,
                      const float* __restrict__ pv, const int* __restrict__ pi,
                      const float* __restrict__ cb, float* __restrict__ out) {
    const int t   = threadIdx.x;
    const int p   = blockIdx.x * 16 + (t >> 4);
    const int l16 = t & 15;
    const int cc  = min(*cnt, CAP);
    if (p >= cc) return;
    const int row = list[p];
    float v   = pv[(size_t)p * RCH];
    int   idx = pi[(size_t)p * RCH];
    #pragma unroll
    for (int c = 1; c < RCH; ++c) {
        const float cv = pv[(size_t)p * RCH + c];
        if (cv < v) { v = cv; idx = pi[(size_t)p * RCH + c]; }
    }
    if (l16 == 0) out[(size_t)N * D + row] = (float)idx;
    const float4* src = reinterpret_cast<const float4*>(cb + (size_t)idx * D);
    float4*       dst = reinterpret_cast<float4*>(out + (size_t)row * D);
    #pragma unroll
    for (int it = 0; it < 4; ++it) dst[l16 + 16 * it] = src[l16 + 16 * it];
}

// ============================================================================
// Fallback (ws too small): round-1 fp32 kernel (verified exact).
// ============================================================================
constexpr int BM = 128, BN = 128, TD = 32, ZS = 260, CS = 36;

__global__ void esq_only(const float* __restrict__ cb, float* __restrict__ esq) {
    const int lane = threadIdx.x & 63;
    const int code = (int)((blockIdx.x * (size_t)blockDim.x + threadIdx.x) >> 6);
    const float4 v = *reinterpret_cast<const float4*>(cb + (size_t)code * D + lane * 4);
    float s = v.x * v.x + v.y * v.y + v.z * v.z + v.w * v.w;
    #pragma unroll
    for (int m = 32; m >= 1; m >>= 1) s += __shfl_xor(s, m);
    if (lane == 0) esq[code] = s;
}

__launch_bounds__(256)
__global__ void vq_kernel(const float* __restrict__ z, const float* __restrict__ cb,
                          const float* __restrict__ esq, float* __restrict__ out) {
    __shared__ float zs[BM * ZS];
    __shared__ float cs[BN * CS];
    const int tid = threadIdx.x;
    const int tx  = tid & 15;
    const int ty  = tid >> 4;
    const size_t row0 = (size_t)blockIdx.x * BM;
    #pragma unroll
    for (int i = 0; i < 32; ++i) {
        int f  = tid + i * 256;
        int r  = f >> 6;
        int c4 = (f & 63) * 4;
        *reinterpret_cast<float4*>(&zs[r * ZS + c4]) =
            *reinterpret_cast<const float4*>(z + (row0 + r) * D + c4);
    }
    float minv[8]; int mini[8];
    #pragma unroll
    for (int i = 0; i < 8; ++i) { minv[i] = 3.4e38f; mini[i] = 0; }
    for (int k0 = 0; k0 < K; k0 += BN) {
        float acc[8][8];
        #pragma unroll
        for (int i = 0; i < 8; ++i)
            #pragma unroll
            for (int j = 0; j < 8; ++j) acc[i][j] = 0.0f;
        for (int dc = 0; dc < D; dc += TD) {
            __syncthreads();
            int c = tid >> 3, c4 = (tid & 7) * 4;
            #pragma unroll
            for (int i = 0; i < 4; ++i)
                *reinterpret_cast<float4*>(&cs[(c + 32 * i) * CS + c4]) =
                    *reinterpret_cast<const float4*>(cb + (size_t)(k0 + c + 32 * i) * D + dc + c4);
            __syncthreads();
            for (int d4 = 0; d4 < TD; d4 += 4) {
                float4 a[8], b[8];
                #pragma unroll
                for (int i = 0; i < 8; ++i)
                    a[i] = *reinterpret_cast<const float4*>(&zs[(ty + 16 * i) * ZS + dc + d4]);
                #pragma unroll
                for (int j = 0; j < 8; ++j)
                    b[j] = *reinterpret_cast<const float4*>(&cs[(tx + 16 * j) * CS + d4]);
                #pragma unroll
                for (int i = 0; i < 8; ++i)
                    #pragma unroll
                    for (int j = 0; j < 8; ++j)
                        acc[i][j] += a[i].x * b[j].x + a[i].y * b[j].y
                                   + a[i].z * b[j].z + a[i].w * b[j].w;
            }
        }
        #pragma unroll
        for (int j = 0; j < 8; ++j) {
            int code = k0 + tx + 16 * j;
            float es = esq[code];
            #pragma unroll
            for (int i = 0; i < 8; ++i) {
                float score = fmaf(-2.0f, acc[i][j], es);
                if (score < minv[i]) { minv[i] = score; mini[i] = code; }
            }
        }
    }
    float* out_idx = out + (size_t)N * D;
    #pragma unroll
    for (int i = 0; i < 8; ++i) {
        float v = minv[i]; int idx = mini[i];
        #pragma unroll
        for (int m = 1; m < 16; m <<= 1) {
            float ov = __shfl_xor(v, m);
            int   oi = __shfl_xor(idx, m);
            if (ov < v || (ov == v && oi < idx)) { v = ov; idx = oi; }
        }
        size_t row = row0 + ty + 16 * i;
        if (tx == 0) out_idx[row] = (float)idx;
        const float4* src = reinterpret_cast<const float4*>(cb + (size_t)idx * D);
        float4*       dst = reinterpret_cast<float4*>(out + row * D);
        #pragma unroll
        for (int t = 0; t < 4; ++t) dst[tx + 16 * t] = src[tx + 16 * t];
    }
}

extern "C" void kernel_launch(void* const* d_in, const int* in_sizes, int n_in,
                              void* d_out, int out_size, void* d_ws, size_t ws_size,
                              hipStream_t stream) {
    const float* z   = (const float*)d_in[0];
    const float* cb  = (const float*)d_in[1];
    float*       out = (float*)d_out;

    const size_t cbt_b  = (size_t)K * 512 * sizeof(f16);       // 8 MB
    const size_t esq_b  = (size_t)K * sizeof(float);           // 32 KB
    const size_t wv_b   = (size_t)3 * N * sizeof(float);       // 384 KB
    const size_t wi_b   = (size_t)3 * N * sizeof(int);         // 384 KB
    const size_t list_b = (size_t)CAP * sizeof(int);           // 64 KB
    const size_t pv_b   = (size_t)CAP * RCH * sizeof(float);   // 2 MB
    const size_t pi_b   = (size_t)CAP * RCH * sizeof(int);     // 2 MB
    const size_t need = cbt_b + esq_b + 2 * wv_b + wi_b + list_b + pv_b + pi_b + 256;

    if (ws_size >= need) {
        char* p = (char*)d_ws;
        f16*   cbt  = (f16*)p;     p += cbt_b;
        float* esqp = (float*)p;   p += esq_b;
        float* wv1  = (float*)p;   p += wv_b;
        int*   wi1  = (int*)p;     p += wi_b;
        float* wv2  = (float*)p;   p += wv_b;
        int*   list = (int*)p;     p += list_b;
        float* pv   = (float*)p;   p += pv_b;
        int*   pi   = (int*)p;     p += pi_b;
        int*   cnt  = (int*)p;

        esq_kernel<<<(K * 64) / 256, 256, 0, stream>>>(cb, esqp, cnt);
        cvt_t<<<(K * 64) / 256, 256, 0, stream>>>(cb, cbt);
        vq16a<<<768, 256, 0, stream>>>(z, cbt, esqp, wv1, wi1, wv2);
        flagmerge<<<N / 16, 256, 0, stream>>>(wv1, wi1, wv2, cb, out, list, cnt);
        rescue<<<(CAP / 128) * RCH, 256, 0, stream>>>(z, cbt, esqp, list, cnt, pv, pi);
        fixup<<<CAP / 16, 256, 0, stream>>>(list, cnt, pv, pi, cb, out);
    } else {
        float* esqp = (float*)d_ws;
        esq_only<<<(K * 64) / 256, 256, 0, stream>>>(cb, esqp);
        vq_kernel<<<N / BM, 256, 0, stream>>>(z, cb, esqp, out);
    }
}